// Round 5
// baseline (341.103 us; speedup 1.0000x reference)
//
#include <hip/hip_runtime.h>
#include <cstdint>
#include <cstddef>

#define DEVI __device__ __forceinline__

typedef __attribute__((ext_vector_type(8))) short short8;
typedef __attribute__((ext_vector_type(4))) float f32x4;

constexpr int Bc = 8, Tc = 2048, Cc = 1024;
constexpr int WKV_L = 32, WKV_NCH = 64;   // T = L * NCH

DEVI unsigned short f2b(float f) {
  unsigned int u = __float_as_uint(f);
  unsigned int r = (u + 0x7FFFu + ((u >> 16) & 1u)) >> 16;  // RNE
  return (unsigned short)r;
}
DEVI float b2f(unsigned short u) {
  return __uint_as_float(((unsigned int)u) << 16);
}

DEVI void gload16(const unsigned short* g, unsigned short* l) {
  __builtin_amdgcn_global_load_lds(
      (const __attribute__((address_space(1))) void*)g,
      (__attribute__((address_space(3))) void*)l, 16, 0, 0);
}

// ---------------- f32 -> bf16 convert (weights) ----------------
__global__ void convert_bf16_kernel(const float* __restrict__ in,
                                    unsigned short* __restrict__ out, int n4) {
  int i = blockIdx.x * blockDim.x + threadIdx.x;
  if (i >= n4) return;
  const float4 v = ((const float4*)in)[i];
  ushort4 o;
  o.x = f2b(v.x); o.y = f2b(v.y); o.z = f2b(v.z); o.w = f2b(v.w);
  ((ushort4*)out)[i] = o;
}

// ---------------- time-mix (k,v,r) + bf16 cast ----------------
__global__ void mix3_kernel(const float* __restrict__ x,
                            const float* __restrict__ tmk,
                            const float* __restrict__ tmv,
                            const float* __restrict__ tmr,
                            unsigned short* __restrict__ kin,
                            unsigned short* __restrict__ vin,
                            unsigned short* __restrict__ rin,
                            long n4) {
  long i = (long)blockIdx.x * blockDim.x + threadIdx.x;
  const long stride = (long)gridDim.x * blockDim.x;
  for (; i < n4; i += stride) {
    const long e = i * 4;
    const int c = (int)(e & (Cc - 1));
    const long bt = e >> 10;
    const int t = (int)(bt & (Tc - 1));
    const float4 xv = *(const float4*)(x + e);
    float4 pv = {0.f, 0.f, 0.f, 0.f};
    if (t > 0) pv = *(const float4*)(x + e - Cc);
    const float4 mk = *(const float4*)(tmk + c);
    const float4 mv = *(const float4*)(tmv + c);
    const float4 mr = *(const float4*)(tmr + c);
    const float* xp = (const float*)&xv;
    const float* pp = (const float*)&pv;
    const float* mkp = (const float*)&mk;
    const float* mvp = (const float*)&mv;
    const float* mrp = (const float*)&mr;
    ushort4 ko, vo, ro;
    unsigned short* kop = (unsigned short*)&ko;
    unsigned short* vop = (unsigned short*)&vo;
    unsigned short* rop = (unsigned short*)&ro;
#pragma unroll
    for (int q = 0; q < 4; ++q) {
      kop[q] = f2b(xp[q] * mkp[q] + pp[q] * (1.f - mkp[q]));
      vop[q] = f2b(xp[q] * mvp[q] + pp[q] * (1.f - mvp[q]));
      rop[q] = f2b(xp[q] * mrp[q] + pp[q] * (1.f - mrp[q]));
    }
    *(ushort4*)(kin + e) = ko;
    *(ushort4*)(vin + e) = vo;
    *(ushort4*)(rin + e) = ro;
  }
}

// ------- 3-deep pipelined bf16 GEMM, counted vmcnt (T3+T4), setprio (T5) ----
// C[M][N] = A[M][K] * W[N][K]^T. 128x128 tile, BK=32, 3 LDS buffers.
// Steady state: 2 STAGEs (8 loads) in flight across barriers; vmcnt(8) waits
// only the current tile's 4 loads. Raw s_barrier (no vmcnt(0) drain).
template <typename OutT>
__global__ __launch_bounds__(256)
void gemm_bf16_3ph(const unsigned short* __restrict__ A,
                   const unsigned short* __restrict__ W,
                   OutT* __restrict__ C_out, int K, int N) {
  constexpr int BK = 32;
  __shared__ alignas(16) unsigned short As[3][128 * BK];
  __shared__ alignas(16) unsigned short Bs[3][128 * BK];
  const int m0 = blockIdx.x * 128;
  const int n0 = blockIdx.y * 128;
  const int tid = threadIdx.x;
  const int lane = tid & 63;
  const int w = tid >> 6;
  const int wr = w >> 1, wc = w & 1;
  const int fr = lane & 15;
  const int sA = lane >> 4;              // 16B k-slot, 0..3
  // staging geometry: 512 chunks of 16B per tile; this thread's 2 chunks
  const int ch0 = (w * 2 + 0) * 64 + lane;
  const int ch1 = (w * 2 + 1) * 64 + lane;
  const int r0 = ch0 >> 2, g0 = ch0 & 3;
  const int r1 = ch1 >> 2, g1 = ch1 & 3;

  f32x4 acc[4][4];
#pragma unroll
  for (int i = 0; i < 4; ++i)
#pragma unroll
    for (int j = 0; j < 4; ++j) acc[i][j] = (f32x4){0.f, 0.f, 0.f, 0.f};

#define STAGE(buf, kt)                                                        \
  {                                                                           \
    gload16(A + (size_t)(m0 + r0) * K + (kt) + g0 * 8, &As[buf][ch0 * 8]);    \
    gload16(W + (size_t)(n0 + r0) * K + (kt) + g0 * 8, &Bs[buf][ch0 * 8]);    \
    gload16(A + (size_t)(m0 + r1) * K + (kt) + g1 * 8, &As[buf][ch1 * 8]);    \
    gload16(W + (size_t)(n0 + r1) * K + (kt) + g1 * 8, &Bs[buf][ch1 * 8]);    \
  }

  const int nt = K / BK;                 // >= 2 always here (K=1024)
  STAGE(0, 0);
  STAGE(1, BK);
  for (int t = 0; t < nt; ++t) {
    const int pf = t + 2;
    if (pf < nt) {
      STAGE(pf % 3, pf * BK);
      asm volatile("s_waitcnt vmcnt(8)" ::: "memory");   // t's 4 loads done
    } else if (pf == nt) {
      asm volatile("s_waitcnt vmcnt(4)" ::: "memory");   // only t+1 in flight
    } else {
      asm volatile("s_waitcnt vmcnt(0)" ::: "memory");   // last tile
    }
    __builtin_amdgcn_s_barrier();        // all waves' t-loads confirmed
    asm volatile("" ::: "memory");
    const int cur = t % 3;
    short8 af[4], bfr[4];
#pragma unroll
    for (int i = 0; i < 4; ++i) {
      af[i]  = *(const short8*)&As[cur][(wr * 64 + i * 16 + fr) * 32 + sA * 8];
      bfr[i] = *(const short8*)&Bs[cur][(wc * 64 + i * 16 + fr) * 32 + sA * 8];
    }
    __builtin_amdgcn_s_setprio(1);
#pragma unroll
    for (int i = 0; i < 4; ++i)
#pragma unroll
      for (int j = 0; j < 4; ++j)
        acc[i][j] = __builtin_amdgcn_mfma_f32_16x16x32_bf16(af[i], bfr[j],
                                                            acc[i][j], 0, 0, 0);
    __builtin_amdgcn_s_setprio(0);
    asm volatile("" ::: "memory");
    __builtin_amdgcn_s_barrier();        // reads of buf[cur] done before reuse
  }
#undef STAGE

  const int orow = (lane >> 4) * 4;
  const int ocol = lane & 15;
#pragma unroll
  for (int i = 0; i < 4; ++i)
#pragma unroll
    for (int j = 0; j < 4; ++j) {
      const size_t rbase = (size_t)(m0 + wr * 64 + i * 16 + orow);
      const int cb = n0 + wc * 64 + j * 16 + ocol;
#pragma unroll
      for (int q = 0; q < 4; ++q) {
        const float vq = acc[i][j][q];
        if constexpr (sizeof(OutT) == 2)
          C_out[(rbase + q) * N + cb] = (OutT)f2b(vq);
        else
          C_out[(rbase + q) * N + cb] = (OutT)vq;
      }
    }
}

// ---------------- WKV chunked scan (bf16 inputs) ----------------
__global__ void wkv_phase1(const unsigned short* __restrict__ keyb,
                           const unsigned short* __restrict__ valb,
                           const float* __restrict__ td,
                           float* __restrict__ s_num,
                           float* __restrict__ s_den,
                           float* __restrict__ s_mx) {
  const int g = blockIdx.x * blockDim.x + threadIdx.x;  // [0, B*NCH*C)
  const int c = g & (Cc - 1);
  const int j = (g / Cc) & (WKV_NCH - 1);
  const int b = g / (Cc * WKV_NCH);
  const float w = -__expf(td[c]);
  float num = 0.f, den = 0.f, mx = -1e38f;
  size_t idx = ((size_t)b * Tc + (size_t)j * WKV_L) * Cc + c;
#pragma unroll 4
  for (int i = 0; i < WKV_L; ++i, idx += Cc) {
    const float kt = b2f(keyb[idx]);
    const float vt = b2f(valb[idx]);
    const float mw = mx + w;
    const float mn = fmaxf(mw, kt);
    const float a1 = __expf(mw - mn);
    const float a2 = __expf(kt - mn);
    num = a1 * num + a2 * vt;
    den = a1 * den + a2;
    mx = mn;
  }
  s_num[g] = num; s_den[g] = den; s_mx[g] = mx;
}

__global__ void wkv_phase2(const float* __restrict__ td,
                           float* __restrict__ s_num,
                           float* __restrict__ s_den,
                           float* __restrict__ s_mx) {
  const int g = blockIdx.x * blockDim.x + threadIdx.x;  // [0, B*C)
  const int c = g & (Cc - 1);
  const int b = g / Cc;
  const float Lw = -__expf(td[c]) * (float)WKV_L;
  float num = 0.f, den = 0.f, mx = -1e38f;
  size_t base = (size_t)b * WKV_NCH * Cc + c;
  for (int j = 0; j < WKV_NCH; ++j) {
    const size_t s = base + (size_t)j * Cc;
    const float ln = s_num[s], ld = s_den[s], lm = s_mx[s];
    s_num[s] = num; s_den[s] = den; s_mx[s] = mx;  // exclusive prefix
    const float md = mx + Lw;
    const float m = fmaxf(md, lm);
    const float e1 = __expf(md - m);
    const float e2 = __expf(lm - m);
    num = e1 * num + e2 * ln;
    den = e1 * den + e2 * ld;
    mx = m;
  }
}

__global__ void wkv_phase3(const unsigned short* __restrict__ keyb,
                           const unsigned short* __restrict__ valb,
                           const unsigned short* __restrict__ recb,
                           const float* __restrict__ td,
                           const float* __restrict__ tf,
                           const float* __restrict__ s_num,
                           const float* __restrict__ s_den,
                           const float* __restrict__ s_mx,
                           unsigned short* __restrict__ rwkv) {
  const int g = blockIdx.x * blockDim.x + threadIdx.x;  // [0, B*NCH*C)
  const int c = g & (Cc - 1);
  const int j = (g / Cc) & (WKV_NCH - 1);
  const int b = g / (Cc * WKV_NCH);
  const float w = -__expf(td[c]);
  const float u = tf[c];
  float num = s_num[g], den = s_den[g], mx = s_mx[g];
  size_t idx = ((size_t)b * Tc + (size_t)j * WKV_L) * Cc + c;
#pragma unroll 2
  for (int i = 0; i < WKV_L; ++i, idx += Cc) {
    const float kt = b2f(keyb[idx]);
    const float vt = b2f(valb[idx]);
    const float rt = b2f(recb[idx]);
    const float ku = kt + u;
    const float mo = fmaxf(mx, ku);
    const float e1 = __expf(mx - mo);
    const float e2 = __expf(ku - mo);
    const float out = (e1 * num + e2 * vt) / (e1 * den + e2);
    const float sr = 1.f / (1.f + __expf(-rt));
    rwkv[idx] = f2b(sr * out);
    const float mw = mx + w;
    const float mn = fmaxf(mw, kt);
    const float a1 = __expf(mw - mn);
    const float a2 = __expf(kt - mn);
    num = a1 * num + a2 * vt;
    den = a1 * den + a2;
    mx = mn;
  }
}

extern "C" void kernel_launch(void* const* d_in, const int* in_sizes, int n_in,
                              void* d_out, int out_size, void* d_ws, size_t ws_size,
                              hipStream_t stream) {
  const float* x   = (const float*)d_in[0];
  const float* Wk  = (const float*)d_in[1];
  const float* Wv  = (const float*)d_in[2];
  const float* Wr  = (const float*)d_in[3];
  const float* Wo  = (const float*)d_in[4];
  const float* td  = (const float*)d_in[5];
  const float* tf  = (const float*)d_in[6];
  const float* tmk = (const float*)d_in[7];
  const float* tmv = (const float*)d_in[8];
  const float* tmr = (const float*)d_in[9];

  const long BT = (long)Bc * Tc;     // 16384
  const long NE = BT * Cc;           // 16,777,216
  const long CC = (long)Cc * Cc;     // 1,048,576

  // Workspace carve (~200 MB)
  char* p = (char*)d_ws;
  unsigned short* Wk_b = (unsigned short*)p; p += CC * 2;
  unsigned short* Wv_b = (unsigned short*)p; p += CC * 2;
  unsigned short* Wr_b = (unsigned short*)p; p += CC * 2;
  unsigned short* Wo_b = (unsigned short*)p; p += CC * 2;
  unsigned short* kin  = (unsigned short*)p; p += NE * 2;
  unsigned short* vin  = (unsigned short*)p; p += NE * 2;
  unsigned short* rin  = (unsigned short*)p; p += NE * 2;
  unsigned short* keyb = (unsigned short*)p; p += NE * 2;
  unsigned short* valb = (unsigned short*)p; p += NE * 2;
  unsigned short* recb = (unsigned short*)p; p += NE * 2;
  // aliases: rwkv reuses kin (dead after key GEMM); s_* reuse vin (dead after
  // value GEMM). 3 x 2MB well within vin's 32MB.
  unsigned short* rwkv = kin;
  const long NS = (long)Bc * WKV_NCH * Cc;  // 524288
  float* s_num = (float*)vin;
  float* s_den = s_num + NS;
  float* s_mx  = s_den + NS;

  // 1. weights -> bf16
  {
    const int n4 = (int)(CC / 4);
    dim3 g((n4 + 255) / 256), b_(256);
    convert_bf16_kernel<<<g, b_, 0, stream>>>(Wk, Wk_b, n4);
    convert_bf16_kernel<<<g, b_, 0, stream>>>(Wv, Wv_b, n4);
    convert_bf16_kernel<<<g, b_, 0, stream>>>(Wr, Wr_b, n4);
    convert_bf16_kernel<<<g, b_, 0, stream>>>(Wo, Wo_b, n4);
  }

  // 2. time-mix + cast
  mix3_kernel<<<2048, 256, 0, stream>>>(x, tmk, tmv, tmr, kin, vin, rin, NE / 4);

  // 3. K/V/R GEMMs (K=1024), bf16 outputs
  {
    dim3 grid((unsigned)(BT / 128), (unsigned)(Cc / 128)), blk(256);
    gemm_bf16_3ph<unsigned short><<<grid, blk, 0, stream>>>(kin, Wk_b, keyb, Cc, Cc);
    gemm_bf16_3ph<unsigned short><<<grid, blk, 0, stream>>>(vin, Wv_b, valb, Cc, Cc);
    gemm_bf16_3ph<unsigned short><<<grid, blk, 0, stream>>>(rin, Wr_b, recb, Cc, Cc);
  }

  // 4. WKV chunked scan + sigmoid gate -> rwkv bf16
  wkv_phase1<<<2048, 256, 0, stream>>>(keyb, valb, td, s_num, s_den, s_mx);
  wkv_phase2<<<32, 256, 0, stream>>>(td, s_num, s_den, s_mx);
  wkv_phase3<<<2048, 256, 0, stream>>>(keyb, valb, recb, td, tf,
                                       s_num, s_den, s_mx, rwkv);

  // 5. output GEMM -> d_out (f32)
  {
    dim3 grid((unsigned)(BT / 128), (unsigned)(Cc / 128)), blk(256);
    gemm_bf16_3ph<float><<<grid, blk, 0, stream>>>(rwkv, Wo_b, (float*)d_out, Cc, Cc);
  }
}

// Round 6
// 266.950 us; speedup vs baseline: 1.2778x; 1.2778x over previous
//
#include <hip/hip_runtime.h>
#include <cstdint>
#include <cstddef>

#define DEVI __device__ __forceinline__

typedef __attribute__((ext_vector_type(8))) short short8;
typedef __attribute__((ext_vector_type(4))) float f32x4;

constexpr int Bc = 8, Tc = 2048, Cc = 1024;
constexpr int WKV_L = 32, WKV_NCH = 64;   // T = L * NCH

DEVI unsigned short f2b(float f) {
  unsigned int u = __float_as_uint(f);
  unsigned int r = (u + 0x7FFFu + ((u >> 16) & 1u)) >> 16;  // RNE
  return (unsigned short)r;
}
DEVI float b2f(unsigned short u) {
  return __uint_as_float(((unsigned int)u) << 16);
}

DEVI void gload16(const unsigned short* g, unsigned short* l) {
  __builtin_amdgcn_global_load_lds(
      (const __attribute__((address_space(1))) void*)g,
      (__attribute__((address_space(3))) void*)l, 16, 0, 0);
}

// ---------------- f32 -> bf16 convert (weights) ----------------
__global__ void convert_bf16_kernel(const float* __restrict__ in,
                                    unsigned short* __restrict__ out, int n4) {
  int i = blockIdx.x * blockDim.x + threadIdx.x;
  if (i >= n4) return;
  const float4 v = ((const float4*)in)[i];
  ushort4 o;
  o.x = f2b(v.x); o.y = f2b(v.y); o.z = f2b(v.z); o.w = f2b(v.w);
  ((ushort4*)out)[i] = o;
}

// ---------------- time-mix (k,v,r) + bf16 cast ----------------
__global__ void mix3_kernel(const float* __restrict__ x,
                            const float* __restrict__ tmk,
                            const float* __restrict__ tmv,
                            const float* __restrict__ tmr,
                            unsigned short* __restrict__ kin,
                            unsigned short* __restrict__ vin,
                            unsigned short* __restrict__ rin,
                            long n4) {
  long i = (long)blockIdx.x * blockDim.x + threadIdx.x;
  const long stride = (long)gridDim.x * blockDim.x;
  for (; i < n4; i += stride) {
    const long e = i * 4;
    const int c = (int)(e & (Cc - 1));
    const long bt = e >> 10;
    const int t = (int)(bt & (Tc - 1));
    const float4 xv = *(const float4*)(x + e);
    float4 pv = {0.f, 0.f, 0.f, 0.f};
    if (t > 0) pv = *(const float4*)(x + e - Cc);
    const float4 mk = *(const float4*)(tmk + c);
    const float4 mv = *(const float4*)(tmv + c);
    const float4 mr = *(const float4*)(tmr + c);
    const float* xp = (const float*)&xv;
    const float* pp = (const float*)&pv;
    const float* mkp = (const float*)&mk;
    const float* mvp = (const float*)&mv;
    const float* mrp = (const float*)&mr;
    ushort4 ko, vo, ro;
    unsigned short* kop = (unsigned short*)&ko;
    unsigned short* vop = (unsigned short*)&vo;
    unsigned short* rop = (unsigned short*)&ro;
#pragma unroll
    for (int q = 0; q < 4; ++q) {
      kop[q] = f2b(xp[q] * mkp[q] + pp[q] * (1.f - mkp[q]));
      vop[q] = f2b(xp[q] * mvp[q] + pp[q] * (1.f - mvp[q]));
      rop[q] = f2b(xp[q] * mrp[q] + pp[q] * (1.f - mrp[q]));
    }
    *(ushort4*)(kin + e) = ko;
    *(ushort4*)(vin + e) = vo;
    *(ushort4*)(rin + e) = ro;
  }
}

// -------- 256x256 / BK=64 / 8-wave bf16 GEMM, swizzled LDS, 1 barrier/iter ---
// C[M][N] = A[M][K] * W[N][K]^T. blockIdx.z selects (A,W,C) triple (batched QKV).
// LDS: [2 dbuf][256 rows][64 k] per operand = 128 KB. Row = 128B = 8 x 16B slots;
// phys slot = logical ^ (row&7): staged via pre-swizzled GLOBAL source (linear
// LDS dest, rule #21), read with the same involution -> conflict-free ds_read.
// Iter: vmcnt(0) [tile t staged a full iter ago -> satisfied]; barrier;
// STAGE(t+1); 64 MFMA. One barrier, one wait per K-tile.
template <typename OutT>
__global__ __launch_bounds__(512, 2)
void gemm256(const unsigned short* __restrict__ A0,
             const unsigned short* __restrict__ W0, OutT* __restrict__ C0,
             const unsigned short* __restrict__ A1,
             const unsigned short* __restrict__ W1, OutT* __restrict__ C1,
             const unsigned short* __restrict__ A2,
             const unsigned short* __restrict__ W2, OutT* __restrict__ C2,
             int K, int N) {
  constexpr int BK = 64;
  __shared__ alignas(16) unsigned short As[2][256 * BK];
  __shared__ alignas(16) unsigned short Bs[2][256 * BK];
  const int z = blockIdx.z;
  const unsigned short* A = z == 0 ? A0 : (z == 1 ? A1 : A2);
  const unsigned short* W = z == 0 ? W0 : (z == 1 ? W1 : W2);
  OutT* C_out = z == 0 ? C0 : (z == 1 ? C1 : C2);
  const int m0 = blockIdx.x * 256;
  const int n0 = blockIdx.y * 256;
  const int tid = threadIdx.x;
  const int lane = tid & 63;
  const int w = tid >> 6;            // 0..7
  const int wm = w >> 2;             // 0..1  (row half)
  const int wn = w & 3;              // 0..3  (col quarter)
  const int fr = lane & 15;
  const int ksl = lane >> 4;         // 0..3: 8-elem k-subslot within 32

  f32x4 acc[8][4];
#pragma unroll
  for (int i = 0; i < 8; ++i)
#pragma unroll
    for (int j = 0; j < 4; ++j) acc[i][j] = (f32x4){0.f, 0.f, 0.f, 0.f};

  // Staging: per operand tile = 256 rows x 8 slots = 2048 x 16B chunks.
  // Wave w covers chunks [w*256, (w+1)*256) in 4 wave-level loads of 64.
  // Lane chunk c = base+lane: row = c>>3, phys slot = c&7,
  // global slot = (c&7) ^ (row&7)  [pre-swizzled source].
#define STAGE(buf, kt)                                                        \
  {                                                                           \
    _Pragma("unroll")                                                         \
    for (int cc = 0; cc < 4; ++cc) {                                          \
      const int c = w * 256 + cc * 64 + lane;                                 \
      const int row = c >> 3;                                                 \
      const int gsl = (c & 7) ^ (row & 7);                                    \
      gload16(A + (size_t)(m0 + row) * K + (kt) + gsl * 8,                    \
              &As[buf][(w * 256 + cc * 64) * 8]);                             \
      gload16(W + (size_t)(n0 + row) * K + (kt) + gsl * 8,                    \
              &Bs[buf][(w * 256 + cc * 64) * 8]);                             \
    }                                                                         \
  }

  const int nt = K / BK;
  STAGE(0, 0);
  int cur = 0;
  for (int t = 0; t < nt; ++t) {
    // tile t's loads were issued a full iteration ago (or prologue):
    asm volatile("s_waitcnt vmcnt(0)" ::: "memory");
    __builtin_amdgcn_s_barrier();   // collective: tile t ready; t-1 reads done
    asm volatile("" ::: "memory");
    if (t + 1 < nt) STAGE(cur ^ 1, (t + 1) * BK);  // overwrites t-1's buffer
#pragma unroll
    for (int ks = 0; ks < 2; ++ks) {
      const int sl = ks * 4 + ksl;   // logical 16B slot
      short8 af[8], bf[4];
#pragma unroll
      for (int i = 0; i < 8; ++i) {
        const int row = wm * 128 + i * 16 + fr;
        af[i] = *(const short8*)&As[cur][row * 64 + ((sl ^ (row & 7)) * 8)];
      }
#pragma unroll
      for (int j = 0; j < 4; ++j) {
        const int row = wn * 64 + j * 16 + fr;
        bf[j] = *(const short8*)&Bs[cur][row * 64 + ((sl ^ (row & 7)) * 8)];
      }
      __builtin_amdgcn_s_setprio(1);
#pragma unroll
      for (int i = 0; i < 8; ++i)
#pragma unroll
        for (int j = 0; j < 4; ++j)
          acc[i][j] = __builtin_amdgcn_mfma_f32_16x16x32_bf16(af[i], bf[j],
                                                              acc[i][j], 0, 0, 0);
      __builtin_amdgcn_s_setprio(0);
    }
    asm volatile("" ::: "memory");
    cur ^= 1;
  }
#undef STAGE

  // C/D layout: col = lane&15, row = (lane>>4)*4 + q
  const int orow = (lane >> 4) * 4;
  const int ocol = lane & 15;
#pragma unroll
  for (int i = 0; i < 8; ++i)
#pragma unroll
    for (int j = 0; j < 4; ++j) {
      const size_t rbase = (size_t)(m0 + wm * 128 + i * 16 + orow);
      const int cb = n0 + wn * 64 + j * 16 + ocol;
#pragma unroll
      for (int q = 0; q < 4; ++q) {
        const float vq = acc[i][j][q];
        if constexpr (sizeof(OutT) == 2)
          C_out[(rbase + q) * N + cb] = (OutT)f2b(vq);
        else
          C_out[(rbase + q) * N + cb] = (OutT)vq;
      }
    }
}

// ---------------- WKV chunked scan (bf16 inputs) ----------------
__global__ void wkv_phase1(const unsigned short* __restrict__ keyb,
                           const unsigned short* __restrict__ valb,
                           const float* __restrict__ td,
                           float* __restrict__ s_num,
                           float* __restrict__ s_den,
                           float* __restrict__ s_mx) {
  const int g = blockIdx.x * blockDim.x + threadIdx.x;  // [0, B*NCH*C)
  const int c = g & (Cc - 1);
  const int j = (g / Cc) & (WKV_NCH - 1);
  const int b = g / (Cc * WKV_NCH);
  const float w = -__expf(td[c]);
  float num = 0.f, den = 0.f, mx = -1e38f;
  size_t idx = ((size_t)b * Tc + (size_t)j * WKV_L) * Cc + c;
#pragma unroll 4
  for (int i = 0; i < WKV_L; ++i, idx += Cc) {
    const float kt = b2f(keyb[idx]);
    const float vt = b2f(valb[idx]);
    const float mw = mx + w;
    const float mn = fmaxf(mw, kt);
    const float a1 = __expf(mw - mn);
    const float a2 = __expf(kt - mn);
    num = a1 * num + a2 * vt;
    den = a1 * den + a2;
    mx = mn;
  }
  s_num[g] = num; s_den[g] = den; s_mx[g] = mx;
}

__global__ void wkv_phase2(const float* __restrict__ td,
                           float* __restrict__ s_num,
                           float* __restrict__ s_den,
                           float* __restrict__ s_mx) {
  const int g = blockIdx.x * blockDim.x + threadIdx.x;  // [0, B*C)
  const int c = g & (Cc - 1);
  const int b = g / Cc;
  const float Lw = -__expf(td[c]) * (float)WKV_L;
  float num = 0.f, den = 0.f, mx = -1e38f;
  size_t base = (size_t)b * WKV_NCH * Cc + c;
  for (int j = 0; j < WKV_NCH; ++j) {
    const size_t s = base + (size_t)j * Cc;
    const float ln = s_num[s], ld = s_den[s], lm = s_mx[s];
    s_num[s] = num; s_den[s] = den; s_mx[s] = mx;  // exclusive prefix
    const float md = mx + Lw;
    const float m = fmaxf(md, lm);
    const float e1 = __expf(md - m);
    const float e2 = __expf(lm - m);
    num = e1 * num + e2 * ln;
    den = e1 * den + e2 * ld;
    mx = m;
  }
}

__global__ void wkv_phase3(const unsigned short* __restrict__ keyb,
                           const unsigned short* __restrict__ valb,
                           const unsigned short* __restrict__ recb,
                           const float* __restrict__ td,
                           const float* __restrict__ tf,
                           const float* __restrict__ s_num,
                           const float* __restrict__ s_den,
                           const float* __restrict__ s_mx,
                           unsigned short* __restrict__ rwkv) {
  const int g = blockIdx.x * blockDim.x + threadIdx.x;  // [0, B*NCH*C)
  const int c = g & (Cc - 1);
  const int j = (g / Cc) & (WKV_NCH - 1);
  const int b = g / (Cc * WKV_NCH);
  const float w = -__expf(td[c]);
  const float u = tf[c];
  float num = s_num[g], den = s_den[g], mx = s_mx[g];
  size_t idx = ((size_t)b * Tc + (size_t)j * WKV_L) * Cc + c;
#pragma unroll 2
  for (int i = 0; i < WKV_L; ++i, idx += Cc) {
    const float kt = b2f(keyb[idx]);
    const float vt = b2f(valb[idx]);
    const float rt = b2f(recb[idx]);
    const float ku = kt + u;
    const float mo = fmaxf(mx, ku);
    const float e1 = __expf(mx - mo);
    const float e2 = __expf(ku - mo);
    const float out = (e1 * num + e2 * vt) / (e1 * den + e2);
    const float sr = 1.f / (1.f + __expf(-rt));
    rwkv[idx] = f2b(sr * out);
    const float mw = mx + w;
    const float mn = fmaxf(mw, kt);
    const float a1 = __expf(mw - mn);
    const float a2 = __expf(kt - mn);
    num = a1 * num + a2 * vt;
    den = a1 * den + a2;
    mx = mn;
  }
}

extern "C" void kernel_launch(void* const* d_in, const int* in_sizes, int n_in,
                              void* d_out, int out_size, void* d_ws, size_t ws_size,
                              hipStream_t stream) {
  const float* x   = (const float*)d_in[0];
  const float* Wk  = (const float*)d_in[1];
  const float* Wv  = (const float*)d_in[2];
  const float* Wr  = (const float*)d_in[3];
  const float* Wo  = (const float*)d_in[4];
  const float* td  = (const float*)d_in[5];
  const float* tf  = (const float*)d_in[6];
  const float* tmk = (const float*)d_in[7];
  const float* tmv = (const float*)d_in[8];
  const float* tmr = (const float*)d_in[9];

  const long BT = (long)Bc * Tc;     // 16384
  const long NE = BT * Cc;           // 16,777,216
  const long CC = (long)Cc * Cc;     // 1,048,576

  // Workspace carve (~200 MB)
  char* p = (char*)d_ws;
  unsigned short* Wk_b = (unsigned short*)p; p += CC * 2;
  unsigned short* Wv_b = (unsigned short*)p; p += CC * 2;
  unsigned short* Wr_b = (unsigned short*)p; p += CC * 2;
  unsigned short* Wo_b = (unsigned short*)p; p += CC * 2;
  unsigned short* kin  = (unsigned short*)p; p += NE * 2;
  unsigned short* vin  = (unsigned short*)p; p += NE * 2;
  unsigned short* rin  = (unsigned short*)p; p += NE * 2;
  unsigned short* keyb = (unsigned short*)p; p += NE * 2;
  unsigned short* valb = (unsigned short*)p; p += NE * 2;
  unsigned short* recb = (unsigned short*)p; p += NE * 2;
  // aliases: rwkv reuses kin (dead after key GEMM); s_* reuse vin (dead after
  // value GEMM). 3 x 2MB well within vin's 32MB.
  unsigned short* rwkv = kin;
  const long NS = (long)Bc * WKV_NCH * Cc;  // 524288
  float* s_num = (float*)vin;
  float* s_den = s_num + NS;
  float* s_mx  = s_den + NS;

  // 1. weights -> bf16
  {
    const int n4 = (int)(CC / 4);
    dim3 g((n4 + 255) / 256), b_(256);
    convert_bf16_kernel<<<g, b_, 0, stream>>>(Wk, Wk_b, n4);
    convert_bf16_kernel<<<g, b_, 0, stream>>>(Wv, Wv_b, n4);
    convert_bf16_kernel<<<g, b_, 0, stream>>>(Wr, Wr_b, n4);
    convert_bf16_kernel<<<g, b_, 0, stream>>>(Wo, Wo_b, n4);
  }

  // 2. time-mix + cast
  mix3_kernel<<<2048, 256, 0, stream>>>(x, tmk, tmv, tmr, kin, vin, rin, NE / 4);

  // 3. K/V/R GEMMs (K=1024), batched via blockIdx.z, bf16 outputs
  {
    dim3 grid((unsigned)(BT / 256), (unsigned)(Cc / 256), 3), blk(512);
    gemm256<unsigned short><<<grid, blk, 0, stream>>>(
        kin, Wk_b, keyb, vin, Wv_b, valb, rin, Wr_b, recb, Cc, Cc);
  }

  // 4. WKV chunked scan + sigmoid gate -> rwkv bf16
  wkv_phase1<<<2048, 256, 0, stream>>>(keyb, valb, td, s_num, s_den, s_mx);
  wkv_phase2<<<32, 256, 0, stream>>>(td, s_num, s_den, s_mx);
  wkv_phase3<<<2048, 256, 0, stream>>>(keyb, valb, recb, td, tf,
                                       s_num, s_den, s_mx, rwkv);

  // 5. output GEMM -> d_out (f32)
  {
    dim3 grid((unsigned)(BT / 256), (unsigned)(Cc / 256), 1), blk(512);
    gemm256<float><<<grid, blk, 0, stream>>>(
        rwkv, Wo_b, (float*)d_out, rwkv, Wo_b, (float*)d_out,
        rwkv, Wo_b, (float*)d_out, Cc, Cc);
  }
}